// Round 5
// baseline (394.315 us; speedup 1.0000x reference)
//
#include <hip/hip_runtime.h>
#include <hip/hip_cooperative_groups.h>
#include <cmath>

namespace cg = cooperative_groups;

// Single cooperative kernel, 4 phases separated by grid.sync():
//  P0: anchor[b,a,:] = sum_seg x / counts   (even blocks; seg via inline bsearch)
//      Wpb = bf16(W_proj), M = W_graph^hops (odd blocks; concurrent with anchor)
//  P1: aggb[b,a,:] = bf16( sum_c M[a,c] * anchor[b,c,:] )
//  P2: Y[r,d] = mfma bf16 GEMM aggb . Wpb^T (f32 out, operands from L2)
//  P3: out[b,t,:] = x[b,t,:] + tanh(gate) * Y[b,assign[t],:]

typedef __attribute__((ext_vector_type(8))) short bf16x8;
typedef __attribute__((ext_vector_type(4))) float f32x4;

#define NB 512
#define NT 256
#define OROWS 8

__device__ inline short f2bf(float f) {            // round-to-nearest-even
    unsigned u = __float_as_uint(f);
    return (short)((u + 0x7FFFu + ((u >> 16) & 1u)) >> 16);
}
__device__ inline int lbound(const int* __restrict__ a, int n, int v) {
    int lo = 0, hi = n;
    while (lo < hi) { int m = (lo + hi) >> 1; if (a[m] < v) lo = m + 1; else hi = m; }
    return lo;
}

__global__ __launch_bounds__(NT) void mega_kernel(
        const float* __restrict__ x, const float* __restrict__ Wp,
        const float* __restrict__ gate, const int* __restrict__ assign,
        const float* __restrict__ Wg, const float* __restrict__ counts,
        const int* __restrict__ hops, float* __restrict__ out,
        float* __restrict__ anchor, float* __restrict__ Y, float* __restrict__ M,
        short* __restrict__ Agb, short* __restrict__ Wpb,
        int B, int T, int D, int A) {
    cg::grid_group grid = cg::this_grid();
    __shared__ float s0[4096];
    __shared__ float s1[4096];
    int bid = blockIdx.x, tid = threadIdx.x;
    int R = B * A;
    int rs = D >> 2;

    // ---------------- P0 ----------------
    if ((bid & 1) == 0) {
        for (int u = bid >> 1; u < R; u += NB / 2) {
            int b = u / A, a = u - (u / A) * A;
            int* sT = (int*)s1;
            if (tid < 2) sT[tid] = lbound(assign, T, a + tid);
            __syncthreads();
            int t0 = sT[0], t1 = sT[1];
            __syncthreads();
            float inv = 1.0f / counts[a];
            const float4* x4 = (const float4*)x + (size_t)b * T * rs;
            float4* an4 = (float4*)anchor + (size_t)u * rs;
            for (int d4 = tid; d4 < rs; d4 += NT) {
                float4 acc = make_float4(0.f, 0.f, 0.f, 0.f);
                const float4* p = x4 + (size_t)t0 * rs + d4;
                int t = t0;
                for (; t + 8 <= t1; t += 8) {
                    float4 v0 = p[0];
                    float4 v1 = p[(size_t)rs];
                    float4 v2 = p[(size_t)2 * rs];
                    float4 v3 = p[(size_t)3 * rs];
                    float4 v4 = p[(size_t)4 * rs];
                    float4 v5 = p[(size_t)5 * rs];
                    float4 v6 = p[(size_t)6 * rs];
                    float4 v7 = p[(size_t)7 * rs];
                    acc.x += ((v0.x + v1.x) + (v2.x + v3.x)) + ((v4.x + v5.x) + (v6.x + v7.x));
                    acc.y += ((v0.y + v1.y) + (v2.y + v3.y)) + ((v4.y + v5.y) + (v6.y + v7.y));
                    acc.z += ((v0.z + v1.z) + (v2.z + v3.z)) + ((v4.z + v5.z) + (v6.z + v7.z));
                    acc.w += ((v0.w + v1.w) + (v2.w + v3.w)) + ((v4.w + v5.w) + (v6.w + v7.w));
                    p += (size_t)8 * rs;
                }
                for (; t < t1; ++t) {
                    float4 v = *p;
                    acc.x += v.x; acc.y += v.y; acc.z += v.z; acc.w += v.w;
                    p += rs;
                }
                an4[d4] = make_float4(acc.x * inv, acc.y * inv, acc.z * inv, acc.w * inv);
            }
        }
    } else {
        long long n8 = (long long)D * D / 8;
        for (long long i = (long long)(bid >> 1) * NT + tid; i < n8; i += (long long)(NB / 2) * NT) {
            const float4* p = (const float4*)Wp + i * 2;
            float4 v0 = p[0], v1 = p[1];
            short4* q = (short4*)Wpb + i * 2;
            short4 o0, o1;
            o0.x = f2bf(v0.x); o0.y = f2bf(v0.y); o0.z = f2bf(v0.z); o0.w = f2bf(v0.w);
            o1.x = f2bf(v1.x); o1.y = f2bf(v1.y); o1.z = f2bf(v1.z); o1.w = f2bf(v1.w);
            q[0] = o0; q[1] = o1;
        }
        if (bid == 1) {
            int n = A * A;
            for (int i = tid; i < n; i += NT) s0[i] = Wg[i];
            int h = hops[0]; if (h < 1) h = 1;
            for (int it = 1; it < h; ++it) {
                __syncthreads();
                for (int i = tid; i < n; i += NT) {
                    int r = i / A, c = i - (i / A) * A;
                    float s = 0.f;
                    for (int k = 0; k < A; ++k) s += Wg[r * A + k] * s0[k * A + c];
                    s1[i] = s;
                }
                __syncthreads();
                for (int i = tid; i < n; i += NT) s0[i] = s1[i];
            }
            __syncthreads();
            for (int i = tid; i < n; i += NT) M[i] = s0[i];
        }
    }
    __threadfence();
    grid.sync();

    // ---------------- P1: agg -> bf16 ----------------
    if ((bid & 1) == 0) {
        for (int u = bid >> 1; u < R; u += NB / 2) {
            int b = u / A, a = u - (u / A) * A;
            if (tid < A) s0[tid] = M[a * A + tid];
            __syncthreads();
            const float4* an4 = (const float4*)anchor + (size_t)b * A * rs;
            short4* ag4 = (short4*)Agb + (size_t)u * rs;
            for (int d4 = tid; d4 < rs; d4 += NT) {
                float4 acc = make_float4(0.f, 0.f, 0.f, 0.f);
                for (int c = 0; c < A; ++c) {
                    float w = s0[c];
                    float4 v = an4[(size_t)c * rs + d4];
                    acc.x += w * v.x; acc.y += w * v.y; acc.z += w * v.z; acc.w += w * v.w;
                }
                short4 o;
                o.x = f2bf(acc.x); o.y = f2bf(acc.y); o.z = f2bf(acc.z); o.w = f2bf(acc.w);
                ag4[d4] = o;
            }
            __syncthreads();
        }
    }
    __threadfence();
    grid.sync();

    // ---------------- P2: Y = Agb . Wpb^T via MFMA ----------------
    {
        int nDt = D / 64;
        int nU = (R / 16) * nDt;
        if ((bid & 1) == 0) {
            for (int u = bid >> 1; u < nU; u += NB / 2) {
                int rt = u / nDt, dt = u - rt * nDt;
                int wave = tid >> 6, lane = tid & 63;
                int rBase = rt * 16;
                int dBase = dt * 64 + wave * 16;
                int rc = lane & 15;
                int kOff = (lane >> 4) * 8;
                const short* aPtr = Agb + (size_t)(rBase + rc) * D + kOff;
                const short* bPtr = Wpb + (size_t)(dBase + rc) * D + kOff;
                f32x4 acc = {0.f, 0.f, 0.f, 0.f};
                #pragma unroll 8
                for (int k = 0; k < D; k += 32) {
                    bf16x8 af = *(const bf16x8*)(aPtr + k);
                    bf16x8 bf = *(const bf16x8*)(bPtr + k);
                    acc = __builtin_amdgcn_mfma_f32_16x16x32_bf16(af, bf, acc, 0, 0, 0);
                }
                int orow = (lane >> 4) * 4;
                #pragma unroll
                for (int j = 0; j < 4; ++j)
                    Y[(size_t)(rBase + orow + j) * D + dBase + rc] = acc[j];
            }
        }
    }
    __threadfence();
    grid.sync();

    // ---------------- P3: out ----------------
    {
        float tg = tanhf(gate[0]);
        int nOut = B * T / OROWS;
        const float4* x4 = (const float4*)x;
        const float4* y4 = (const float4*)Y;
        float4* o4 = (float4*)out;
        for (int u = bid; u < nOut; u += NB) {
            int bt0 = u * OROWS;
            #pragma unroll
            for (int r = 0; r < OROWS; ++r) {
                int bt = bt0 + r;
                int b = bt / T;
                int t = bt - b * T;
                int a = assign[t];
                const float4* yr = y4 + ((size_t)b * A + a) * rs;
                for (int d4 = tid; d4 < rs; d4 += NT) {
                    float4 xv = x4[(size_t)bt * rs + d4];
                    float4 yv = yr[d4];
                    o4[(size_t)bt * rs + d4] = make_float4(xv.x + tg * yv.x, xv.y + tg * yv.y,
                                                           xv.z + tg * yv.z, xv.w + tg * yv.w);
                }
            }
        }
    }
}

extern "C" void kernel_launch(void* const* d_in, const int* in_sizes, int n_in,
                              void* d_out, int out_size, void* d_ws, size_t ws_size,
                              hipStream_t stream) {
    const float* x      = (const float*)d_in[0];
    const float* Wp     = (const float*)d_in[1];
    const float* gate   = (const float*)d_in[2];
    const int*   assign = (const int*)d_in[3];
    const float* Wg     = (const float*)d_in[4];
    const float* counts = (const float*)d_in[5];
    const int*   hops   = (const int*)d_in[6];
    float* out = (float*)d_out;

    int T = in_sizes[3];
    int A = in_sizes[5];
    int D = (int)(sqrt((double)in_sizes[1]) + 0.5);
    int B = (int)(in_sizes[0] / ((long long)T * D));
    int R = B * A;

    // workspace layout (16B-aligned chunks)
    float* anchor = (float*)d_ws;                       // R*D f32
    float* Y      = anchor + (size_t)R * D;             // R*D f32
    float* M      = Y + (size_t)R * D;                  // A*A f32
    short* Agb    = (short*)(M + (size_t)A * A);        // R*D bf16
    short* Wpb    = Agb + (size_t)R * D;                // D*D bf16

    void* args[] = {
        (void*)&x, (void*)&Wp, (void*)&gate, (void*)&assign, (void*)&Wg,
        (void*)&counts, (void*)&hops, (void*)&out,
        (void*)&anchor, (void*)&Y, (void*)&M, (void*)&Agb, (void*)&Wpb,
        (void*)&B, (void*)&T, (void*)&D, (void*)&A
    };
    hipLaunchCooperativeKernel((const void*)mega_kernel, dim3(NB), dim3(NT),
                               args, 0, stream);
}

// Round 6
// 60.090 us; speedup vs baseline: 6.5621x; 6.5621x over previous
//
#include <hip/hip_runtime.h>
#include <cmath>

// Pipeline (4 graph nodes; M-mix commutes with projection: Y_b = M @ (anchor_b @ Wp^T)):
//  N1 prepanchor: blocks 0..R-1:   anchorb[b,a,:] = bf16( sum_seg x / counts[a] )
//                 blocks R..R+255: Wpb = bf16(W_proj)
//                 block  R+256:    M = W_graph ^ hops (hops read on device)
//  N2 zgemm:      Z[r,d] = anchorb[r,:] . Wpb[d,:]   (mfma bf16, f32 out, no LDS)
//  N3 mix:        Y[b,a,:] = sum_c M[a,c] * Z[b,c,:] (f32, L2-resident)
//  N4 out:        out[b,t,:] = x[b,t,:] + tanh(gate) * Y[b,assign[t],:]

typedef __attribute__((ext_vector_type(8))) short bf16x8;
typedef __attribute__((ext_vector_type(4))) float f32x4;

#define OROWS 8

__device__ inline short f2bf(float f) {            // round-to-nearest-even
    unsigned u = __float_as_uint(f);
    return (short)((u + 0x7FFFu + ((u >> 16) & 1u)) >> 16);
}
__device__ inline int lbound(const int* __restrict__ a, int n, int v) {
    int lo = 0, hi = n;
    while (lo < hi) { int m = (lo + hi) >> 1; if (a[m] < v) lo = m + 1; else hi = m; }
    return lo;
}

// N1: blocks 0..R-1 anchor->bf16; R..R+255 Wp->bf16; R+256 M=W^h.
__global__ __launch_bounds__(256) void prepanchor_kernel(
        const float* __restrict__ x, const float* __restrict__ counts,
        const int* __restrict__ assign, const float* __restrict__ Wg,
        const int* __restrict__ hops, const float* __restrict__ Wp,
        short* __restrict__ anchorb, short* __restrict__ Wpb, float* __restrict__ M,
        int T, int D, int A, int R) {
    __shared__ float s0[4096];
    __shared__ float s1[4096];
    int bid = blockIdx.x, tid = threadIdx.x;
    int rs = D >> 2;
    if (bid < R) {
        int b = bid / A, a = bid - (bid / A) * A;
        int* sT = (int*)s1;
        if (tid < 2) sT[tid] = lbound(assign, T, a + tid);
        __syncthreads();
        int t0 = sT[0], t1 = sT[1];
        float inv = 1.0f / counts[a];
        const float4* x4 = (const float4*)x + (size_t)b * T * rs;
        short4* an4 = (short4*)anchorb + (size_t)bid * rs;
        for (int d4 = tid; d4 < rs; d4 += 256) {
            float4 acc = make_float4(0.f, 0.f, 0.f, 0.f);
            const float4* p = x4 + (size_t)t0 * rs + d4;
            int t = t0;
            for (; t + 8 <= t1; t += 8) {
                float4 v0 = p[0];
                float4 v1 = p[(size_t)rs];
                float4 v2 = p[(size_t)2 * rs];
                float4 v3 = p[(size_t)3 * rs];
                float4 v4 = p[(size_t)4 * rs];
                float4 v5 = p[(size_t)5 * rs];
                float4 v6 = p[(size_t)6 * rs];
                float4 v7 = p[(size_t)7 * rs];
                acc.x += ((v0.x + v1.x) + (v2.x + v3.x)) + ((v4.x + v5.x) + (v6.x + v7.x));
                acc.y += ((v0.y + v1.y) + (v2.y + v3.y)) + ((v4.y + v5.y) + (v6.y + v7.y));
                acc.z += ((v0.z + v1.z) + (v2.z + v3.z)) + ((v4.z + v5.z) + (v6.z + v7.z));
                acc.w += ((v0.w + v1.w) + (v2.w + v3.w)) + ((v4.w + v5.w) + (v6.w + v7.w));
                p += (size_t)8 * rs;
            }
            for (; t < t1; ++t) {
                float4 v = *p;
                acc.x += v.x; acc.y += v.y; acc.z += v.z; acc.w += v.w;
                p += rs;
            }
            short4 o;
            o.x = f2bf(acc.x * inv); o.y = f2bf(acc.y * inv);
            o.z = f2bf(acc.z * inv); o.w = f2bf(acc.w * inv);
            an4[d4] = o;
        }
    } else if (bid < R + 256) {
        long long n8 = (long long)D * D / 8;
        for (long long i = (long long)(bid - R) * 256 + tid; i < n8; i += 256LL * 256LL) {
            const float4* p = (const float4*)Wp + i * 2;
            float4 v0 = p[0], v1 = p[1];
            short4* q = (short4*)Wpb + i * 2;
            short4 o0, o1;
            o0.x = f2bf(v0.x); o0.y = f2bf(v0.y); o0.z = f2bf(v0.z); o0.w = f2bf(v0.w);
            o1.x = f2bf(v1.x); o1.y = f2bf(v1.y); o1.z = f2bf(v1.z); o1.w = f2bf(v1.w);
            q[0] = o0; q[1] = o1;
        }
    } else {
        int n = A * A;
        for (int i = tid; i < n; i += 256) s0[i] = Wg[i];
        int h = hops[0]; if (h < 1) h = 1;
        for (int it = 1; it < h; ++it) {
            __syncthreads();
            for (int i = tid; i < n; i += 256) {
                int r = i / A, c = i - (i / A) * A;
                float s = 0.f;
                for (int k = 0; k < A; ++k) s += Wg[r * A + k] * s0[k * A + c];
                s1[i] = s;
            }
            __syncthreads();
            for (int i = tid; i < n; i += 256) s0[i] = s1[i];
        }
        __syncthreads();
        for (int i = tid; i < n; i += 256) M[i] = s0[i];
    }
}

// N2: Z[r,d] = anchorb[r,:] . Wpb[d,:] via mfma_f32_16x16x32_bf16, operands from L2.
// Block = 4 waves; tile 16 r x 64 d (wave w owns d-offset w*16).
// A/B-frag: lane holds row (lane&15), k = (lane>>4)*8 .. +8.  D: col=lane&15, row=(lane>>4)*4+j.
__global__ __launch_bounds__(256) void zgemm_kernel(
        const short* __restrict__ Agb, const short* __restrict__ Wpb,
        float* __restrict__ Z, int D) {
    int wave = threadIdx.x >> 6;
    int lane = threadIdx.x & 63;
    int rBase = blockIdx.x * 16;
    int dBase = blockIdx.y * 64 + wave * 16;
    int rc = lane & 15;
    int kOff = (lane >> 4) * 8;
    const short* aPtr = Agb + (size_t)(rBase + rc) * D + kOff;
    const short* bPtr = Wpb + (size_t)(dBase + rc) * D + kOff;
    f32x4 acc = {0.f, 0.f, 0.f, 0.f};
    #pragma unroll 8
    for (int k = 0; k < D; k += 32) {
        bf16x8 af = *(const bf16x8*)(aPtr + k);
        bf16x8 bf = *(const bf16x8*)(bPtr + k);
        acc = __builtin_amdgcn_mfma_f32_16x16x32_bf16(af, bf, acc, 0, 0, 0);
    }
    int orow = (lane >> 4) * 4;
    #pragma unroll
    for (int j = 0; j < 4; ++j)
        Z[(size_t)(rBase + orow + j) * D + dBase + rc] = acc[j];
}

// N3: Y[b,a,:] = sum_c M[a,c] * Z[b,c,:]   (grid = R blocks; Z is L2-resident)
__global__ __launch_bounds__(256) void mix_kernel(
        const float* __restrict__ Z, const float* __restrict__ M,
        float* __restrict__ Y, int D, int A) {
    int b = blockIdx.x / A, a = blockIdx.x - (blockIdx.x / A) * A;
    __shared__ float row[64];
    if (threadIdx.x < A) row[threadIdx.x] = M[a * A + threadIdx.x];
    __syncthreads();
    int rs = D >> 2;
    const float4* z4 = (const float4*)Z + (size_t)b * A * rs;
    float4* y4 = (float4*)Y + (size_t)blockIdx.x * rs;
    for (int d4 = threadIdx.x; d4 < rs; d4 += 256) {
        float4 acc = make_float4(0.f, 0.f, 0.f, 0.f);
        for (int c = 0; c < A; ++c) {
            float w = row[c];
            float4 v = z4[(size_t)c * rs + d4];
            acc.x += w * v.x; acc.y += w * v.y; acc.z += w * v.z; acc.w += w * v.w;
        }
        y4[d4] = acc;
    }
}

// N4: out[b,t,:] = x[b,t,:] + tg * Y[b,assign[t],:]
__global__ __launch_bounds__(256) void out_kernel(
        const float* __restrict__ x, const float* __restrict__ Y,
        const int* __restrict__ assign, const float* __restrict__ gate,
        float* __restrict__ out, int T, int D, int A) {
    float tg = tanhf(gate[0]);
    int rs = D >> 2;
    int bt0 = blockIdx.x * OROWS;
    const float4* x4 = (const float4*)x;
    const float4* y4 = (const float4*)Y;
    float4* o4 = (float4*)out;
    #pragma unroll
    for (int r = 0; r < OROWS; ++r) {
        int bt = bt0 + r;
        int b = bt / T;
        int t = bt - b * T;
        int a = assign[t];
        const float4* yr = y4 + ((size_t)b * A + a) * rs;
        for (int d4 = threadIdx.x; d4 < rs; d4 += 256) {
            float4 xv = x4[(size_t)bt * rs + d4];
            float4 yv = yr[d4];
            o4[(size_t)bt * rs + d4] = make_float4(xv.x + tg * yv.x, xv.y + tg * yv.y,
                                                   xv.z + tg * yv.z, xv.w + tg * yv.w);
        }
    }
}

extern "C" void kernel_launch(void* const* d_in, const int* in_sizes, int n_in,
                              void* d_out, int out_size, void* d_ws, size_t ws_size,
                              hipStream_t stream) {
    const float* x      = (const float*)d_in[0];
    const float* Wp     = (const float*)d_in[1];
    const float* gate   = (const float*)d_in[2];
    const int*   assign = (const int*)d_in[3];
    const float* Wg     = (const float*)d_in[4];
    const float* counts = (const float*)d_in[5];
    const int*   hops   = (const int*)d_in[6];
    float* out = (float*)d_out;

    int T = in_sizes[3];
    int A = in_sizes[5];
    int D = (int)(sqrt((double)in_sizes[1]) + 0.5);
    int B = (int)(in_sizes[0] / ((long long)T * D));
    int R = B * A;

    // workspace layout (16B-aligned chunks)
    float* Z       = (float*)d_ws;                      // R*D f32
    float* Y       = Z + (size_t)R * D;                 // R*D f32
    float* M       = Y + (size_t)R * D;                 // A*A f32
    short* anchorb = (short*)(M + (size_t)A * A);       // R*D bf16
    short* Wpb     = anchorb + (size_t)R * D;           // D*D bf16

    prepanchor_kernel<<<R + 257, 256, 0, stream>>>(x, counts, assign, Wg, hops, Wp,
                                                   anchorb, Wpb, M, T, D, A, R);
    dim3 g(R / 16, D / 64);
    zgemm_kernel<<<g, 256, 0, stream>>>(anchorb, Wpb, Z, D);
    mix_kernel<<<R, 256, 0, stream>>>(Z, M, Y, D, A);
    out_kernel<<<B * T / OROWS, 256, 0, stream>>>(x, Y, assign, gate, out, T, D, A);
}